// Round 1
// baseline (488.533 us; speedup 1.0000x reference)
//
#include <hip/hip_runtime.h>
#include <cstdint>
#include <cstddef>

#define B_POINTS 131072
#define D_DIM    128
#define G_GROUPS 128
#define NLABELS  8
#define GD       (G_GROUPS * D_DIM)   // 16384

// ---------------------------------------------------------------------------
// K_hist: histogram of group ids over B points -> counts[128] (int)
// ---------------------------------------------------------------------------
__global__ __launch_bounds__(256) void k_hist(const int* __restrict__ subject,
                                              const int* __restrict__ labels,
                                              int* __restrict__ counts) {
    __shared__ int h[G_GROUPS];
    int t = threadIdx.x;
    if (t < G_GROUPS) h[t] = 0;
    __syncthreads();
    for (int i = blockIdx.x * blockDim.x + t; i < B_POINTS; i += gridDim.x * blockDim.x) {
        int g = subject[i] * NLABELS + labels[i];
        atomicAdd(&h[g], 1);
    }
    __syncthreads();
    if (t < G_GROUPS) atomicAdd(&counts[t], h[t]);
}

// ---------------------------------------------------------------------------
// K_psum: per-block partial centroid sums. Wave-per-point: lane l loads
// float4 at X + b*256 + 4*l (covers BOTH views of point b: 1 KiB contiguous).
// Accumulate into 64 KiB LDS [G][D] via LDS float atomics (2-way conflict,
// free per m136), then dump deterministic partial slab to ws.
// ---------------------------------------------------------------------------
__global__ __launch_bounds__(512) void k_psum(const float* __restrict__ X,
                                              const int* __restrict__ subject,
                                              const int* __restrict__ labels,
                                              float* __restrict__ part) {
    __shared__ float acc[GD];   // exactly 64 KiB
    int t = threadIdx.x;
    for (int i = t; i < GD; i += blockDim.x) acc[i] = 0.f;
    __syncthreads();

    const int lane = t & 63;
    const int wid  = (blockIdx.x * blockDim.x + t) >> 6;
    const int nw   = (gridDim.x * blockDim.x) >> 6;
    const int col  = (lane & 31) * 4;            // dim offset within D

    for (int base = wid * 4; base < B_POINTS; base += nw * 4) {
        float4 x[4];
        int    g[4];
#pragma unroll
        for (int j = 0; j < 4; ++j) {
            int b = base + j;
            if (b < B_POINTS) {
                x[j] = *(const float4*)(X + (size_t)b * 256 + lane * 4);
                g[j] = subject[b] * NLABELS + labels[b];
            } else {
                g[j] = -1;
            }
        }
#pragma unroll
        for (int j = 0; j < 4; ++j) {
            if (g[j] >= 0) {
                float* a = &acc[g[j] * D_DIM + col];
                atomicAdd(a + 0, x[j].x);
                atomicAdd(a + 1, x[j].y);
                atomicAdd(a + 2, x[j].z);
                atomicAdd(a + 3, x[j].w);
            }
        }
    }
    __syncthreads();
    float* dst = part + (size_t)blockIdx.x * GD;
    for (int i = t; i < GD; i += blockDim.x) dst[i] = acc[i];
}

// ---------------------------------------------------------------------------
// K_reduce: sum P partial slabs -> centroid[G][D] (divided by counts), and
// countsf[g] = 2*counts[g] (both views share the group).
// ---------------------------------------------------------------------------
__global__ __launch_bounds__(256) void k_reduce(const float* __restrict__ part,
                                                const int* __restrict__ counts,
                                                float* __restrict__ centroid,
                                                float* __restrict__ countsf,
                                                int P) {
    int t = blockIdx.x * blockDim.x + threadIdx.x;
    if (t >= GD) return;
    float s = 0.f;
    for (int p = 0; p < P; ++p) s += part[(size_t)p * GD + t];
    int g = t >> 7;
    float c = 2.0f * (float)counts[g];
    centroid[t] = (c > 0.f) ? (s / c) : 0.f;
    if (t < G_GROUPS) countsf[t] = 2.0f * (float)counts[t];
}

// ---------------------------------------------------------------------------
// K_dist: second pass. Wave-per-point; lanes 0..31 = view0 dims, 32..63 =
// view1 dims. Squared distance reduced within each 32-lane half via
// __shfl_xor butterfly; sqrt(sqrt(.)) accumulated per-group in LDS, then
// deterministic partial row to ws. Centroid (64 KiB) read from global —
// stays L1/L2 hot.
// ---------------------------------------------------------------------------
__global__ __launch_bounds__(512) void k_dist(const float* __restrict__ X,
                                              const int* __restrict__ subject,
                                              const int* __restrict__ labels,
                                              const float* __restrict__ centroid,
                                              float* __restrict__ dpart) {
    __shared__ float dsum[G_GROUPS];
    int t = threadIdx.x;
    if (t < G_GROUPS) dsum[t] = 0.f;
    __syncthreads();

    const int lane = t & 63;
    const int wid  = (blockIdx.x * blockDim.x + t) >> 6;
    const int nw   = (gridDim.x * blockDim.x) >> 6;
    const int col  = (lane & 31) * 4;

    for (int base = wid * 4; base < B_POINTS; base += nw * 4) {
        float4 x[4], c[4];
        int    g[4];
#pragma unroll
        for (int j = 0; j < 4; ++j) {
            int b = base + j;
            if (b < B_POINTS) {
                g[j] = subject[b] * NLABELS + labels[b];
                x[j] = *(const float4*)(X + (size_t)b * 256 + lane * 4);
                c[j] = *(const float4*)(centroid + g[j] * D_DIM + col);
            } else {
                g[j] = -1;
            }
        }
#pragma unroll
        for (int j = 0; j < 4; ++j) {
            if (g[j] >= 0) {
                float dx = x[j].x - c[j].x;
                float dy = x[j].y - c[j].y;
                float dz = x[j].z - c[j].z;
                float dw = x[j].w - c[j].w;
                float d = dx * dx + dy * dy + dz * dz + dw * dw;
                // reduce within each 32-lane half (xor masks < 32)
#pragma unroll
                for (int m = 1; m <= 16; m <<= 1) d += __shfl_xor(d, m);
                float sd = sqrtf(sqrtf(d));    // sqrt(norm)
                if ((lane & 31) == 0) atomicAdd(&dsum[g[j]], sd);
            }
        }
    }
    __syncthreads();
    if (t < G_GROUPS) dpart[(size_t)blockIdx.x * G_GROUPS + t] = dsum[t];
}

// ---------------------------------------------------------------------------
// K_final: single block, 128 threads (thread t owns group t).
// dens -> where(counts>1) -> percentile clip (jnp linear interp) ->
// normalize -> sim = exp(centroid.coc/dens) -> out = -(mean(sim - max)).
// ---------------------------------------------------------------------------
__global__ __launch_bounds__(128) void k_final(const float* __restrict__ dpart,
                                               int P,
                                               const float* __restrict__ countsf,
                                               const float* __restrict__ centroid,
                                               float* __restrict__ out) {
    __shared__ float srt[G_GROUPS];
    __shared__ float red[G_GROUPS];
    __shared__ float coc[D_DIM];
    int t = threadIdx.x;

    float ds = 0.f;
    for (int p = 0; p < P; ++p) ds += dpart[(size_t)p * G_GROUPS + t];
    float cnt  = countsf[t];
    float dens = (cnt > 1.f) ? (ds / cnt) / logf(cnt + 10.f) : 0.f;

    // dmax over (counts>1 ? dens : 0)
    red[t] = dens;
    __syncthreads();
    for (int s = 64; s > 0; s >>= 1) {
        if (t < s) red[t] = fmaxf(red[t], red[t + s]);
        __syncthreads();
    }
    float dmax = red[0];
    __syncthreads();
    if (!(cnt > 1.f)) dens = dmax;

    // bitonic sort of dens copy (ascending)
    srt[t] = dens;
    __syncthreads();
    for (int k = 2; k <= G_GROUPS; k <<= 1) {
        for (int j = k >> 1; j > 0; j >>= 1) {
            int ixj = t ^ j;
            if (ixj > t) {
                float a = srt[t], b = srt[ixj];
                bool up = ((t & k) == 0);
                if ((a > b) == up) { srt[t] = b; srt[ixj] = a; }
            }
            __syncthreads();
        }
    }

    // jnp.percentile linear interpolation: pos = q/100 * (n-1)
    double p10 = 0.10 * 127.0;  // 12.7
    double p90 = 0.90 * 127.0;  // 114.3
    int   i10 = (int)p10,            i90 = (int)p90;
    float f10 = (float)(p10 - i10),  f90 = (float)(p90 - i90);
    float lo = srt[i10] + f10 * (srt[i10 + 1] - srt[i10]);
    float hi = srt[i90] + f90 * (srt[i90 + 1] - srt[i90]);
    dens = fminf(fmaxf(dens, lo), hi);

    // mean of clipped dens
    red[t] = dens;
    __syncthreads();
    for (int s = 64; s > 0; s >>= 1) {
        if (t < s) red[t] += red[t + s];
        __syncthreads();
    }
    float dmean = red[0] / 128.f;
    __syncthreads();
    dens = 0.1f * dens / dmean;

    // centroid of centroids
    float cs = 0.f;
    for (int g = 0; g < G_GROUPS; ++g) cs += centroid[g * D_DIM + t];
    coc[t] = cs / 128.f;
    __syncthreads();

    // dot(centroid[t], coc), sim, max, mean
    float dot = 0.f;
    for (int d = 0; d < D_DIM; ++d) dot += centroid[t * D_DIM + d] * coc[d];
    float sim = expf(dot / dens);

    red[t] = sim;
    __syncthreads();
    for (int s = 64; s > 0; s >>= 1) {
        if (t < s) red[t] = fmaxf(red[t], red[t + s]);
        __syncthreads();
    }
    float smax = red[0];
    __syncthreads();
    red[t] = sim - smax;
    __syncthreads();
    for (int s = 64; s > 0; s >>= 1) {
        if (t < s) red[t] += red[t + s];
        __syncthreads();
    }
    if (t == 0) out[0] = -(red[0] / 128.f);
}

// ---------------------------------------------------------------------------
extern "C" void kernel_launch(void* const* d_in, const int* in_sizes, int n_in,
                              void* d_out, int out_size, void* d_ws, size_t ws_size,
                              hipStream_t stream) {
    const float* X       = (const float*)d_in[0];
    const int*   subject = (const int*)d_in[1];
    const int*   labels  = (const int*)d_in[2];
    float*       out     = (float*)d_out;
    char*        ws      = (char*)d_ws;

    const size_t slab  = (size_t)GD * sizeof(float);   // 65536 B per partial
    const size_t fixed = 65536 /*centroid*/ + 512 /*counts*/ + 512 /*countsf*/;
    int P = 256;
    while (P > 1 && (size_t)P * (slab + 512) + fixed > ws_size) P >>= 1;

    float* part     = (float*)ws;
    float* dpart    = (float*)(ws + (size_t)P * slab);
    float* centroid = (float*)(ws + (size_t)P * slab + (size_t)P * 512);
    int*   counts   = (int*)((char*)centroid + 65536);
    float* countsf  = (float*)((char*)counts + 512);

    hipMemsetAsync(counts, 0, 512, stream);
    k_hist<<<256, 256, 0, stream>>>(subject, labels, counts);
    k_psum<<<P, 512, 0, stream>>>(X, subject, labels, part);
    k_reduce<<<(GD + 255) / 256, 256, 0, stream>>>(part, counts, centroid, countsf, P);
    k_dist<<<P, 512, 0, stream>>>(X, subject, labels, centroid, dpart);
    k_final<<<1, 128, 0, stream>>>(dpart, P, countsf, centroid, out);
}

// Round 2
// 351.229 us; speedup vs baseline: 1.3909x; 1.3909x over previous
//
#include <hip/hip_runtime.h>
#include <cstdint>
#include <cstddef>

#define BPTS  131072
#define D_DIM 128
#define G_GR  128
#define NL    8
#define NSLC  16            // slices per group -> 2048 blocks for heavy passes
#define PERMBUF 256         // LDS perm cache; max slice len ~72 for B=131072

// ---------------------------------------------------------------------------
// k_hist: counts[g] = #points in group g
// ---------------------------------------------------------------------------
__global__ __launch_bounds__(256) void k_hist(const int* __restrict__ sub,
                                              const int* __restrict__ lab,
                                              int* __restrict__ counts) {
    __shared__ int h[G_GR];
    int t = threadIdx.x;
    if (t < G_GR) h[t] = 0;
    __syncthreads();
    for (int i = blockIdx.x * 256 + t; i < BPTS; i += gridDim.x * 256)
        atomicAdd(&h[sub[i] * NL + lab[i]], 1);
    __syncthreads();
    if (t < G_GR) atomicAdd(&counts[t], h[t]);
}

// ---------------------------------------------------------------------------
// k_prefix: exclusive prefix of counts -> offsets, cursor copy, countsf=2n
// ---------------------------------------------------------------------------
__global__ __launch_bounds__(128) void k_prefix(const int* __restrict__ counts,
                                                int* __restrict__ offsets,
                                                int* __restrict__ cursor,
                                                float* __restrict__ countsf) {
    int t = threadIdx.x;
    int o = 0;
    for (int j = 0; j < t; ++j) o += counts[j];
    offsets[t] = o;
    cursor[t]  = o;
    countsf[t] = 2.0f * (float)counts[t];
}

// ---------------------------------------------------------------------------
// k_slot: perm[slot] = point index, grouped by g (order within group arbitrary)
// ---------------------------------------------------------------------------
__global__ __launch_bounds__(256) void k_slot(const int* __restrict__ sub,
                                              const int* __restrict__ lab,
                                              int* __restrict__ cursor,
                                              int* __restrict__ perm) {
    for (int i = blockIdx.x * 256 + threadIdx.x; i < BPTS; i += gridDim.x * 256) {
        int g = sub[i] * NL + lab[i];
        int s = atomicAdd(&cursor[g], 1);
        perm[s] = i;
    }
}

// ---------------------------------------------------------------------------
// k_psum: block (g,s) sums its slice of group g's points into a 128-float
// partial (views folded). Wave-per-point float4 loads, register accumulate,
// zero atomics.
// ---------------------------------------------------------------------------
__global__ __launch_bounds__(512) void k_psum(const float4* __restrict__ X4,
                                              const int* __restrict__ perm,
                                              const int* __restrict__ offsets,
                                              const int* __restrict__ counts,
                                              float* __restrict__ part) {
    __shared__ int   pbuf[PERMBUF];
    __shared__ float red[8 * 256];       // 8 KiB
    int g = blockIdx.x / NSLC, s = blockIdx.x % NSLC;
    int off = offsets[g], len = counts[g];
    int lo = off + (int)(((long)len * s) / NSLC);
    int hi = off + (int)(((long)len * (s + 1)) / NSLC);
    int slen = hi - lo;
    int t = threadIdx.x, lane = t & 63, w = t >> 6;

    for (int j = t; j < slen; j += 512) pbuf[j] = perm[lo + j];
    __syncthreads();

    float4 acc = make_float4(0.f, 0.f, 0.f, 0.f);
    for (int i = w * 4; i < slen; i += 32) {
#pragma unroll
        for (int u = 0; u < 4; ++u) {
            int j  = i + u;
            int jj = (j < slen) ? j : (slen - 1);
            int b  = pbuf[jj];
            float4 x = X4[(size_t)b * 64 + lane];
            if (j < slen) { acc.x += x.x; acc.y += x.y; acc.z += x.z; acc.w += x.w; }
        }
    }
    red[w * 256 + lane * 4 + 0] = acc.x;
    red[w * 256 + lane * 4 + 1] = acc.y;
    red[w * 256 + lane * 4 + 2] = acc.z;
    red[w * 256 + lane * 4 + 3] = acc.w;
    __syncthreads();
    if (t < 256) {                        // fold 8 wave copies
        float v = 0.f;
        for (int r = 0; r < 8; ++r) v += red[r * 256 + t];
        red[t] = v;
    }
    __syncthreads();
    if (t < 128)                          // fold the two views
        part[(size_t)(g * NSLC + s) * 128 + t] = red[t] + red[t + 128];
}

// ---------------------------------------------------------------------------
// k_reduce: centroid[g][d] = sum of slice partials / (2n)
// ---------------------------------------------------------------------------
__global__ __launch_bounds__(256) void k_reduce(const float* __restrict__ part,
                                                const int* __restrict__ counts,
                                                float* __restrict__ centroid) {
    int t = blockIdx.x * 256 + threadIdx.x;
    if (t >= G_GR * D_DIM) return;
    int g = t >> 7, d = t & 127;
    float v = 0.f;
    for (int s = 0; s < NSLC; ++s) v += part[(size_t)(g * NSLC + s) * 128 + d];
    int n = counts[g];
    centroid[t] = (n > 0) ? v / (2.0f * (float)n) : 0.f;
}

// ---------------------------------------------------------------------------
// k_dist: block (g,s): per-point per-view ||x-c|| via 32-lane shfl butterfly,
// accumulate sqrt(norm)^(1/2)... i.e. sqrt(dist) with dist=||x-c||; partial
// sum per block. Centroid loop-invariant in registers.
// ---------------------------------------------------------------------------
__global__ __launch_bounds__(512) void k_dist(const float4* __restrict__ X4,
                                              const int* __restrict__ perm,
                                              const int* __restrict__ offsets,
                                              const int* __restrict__ counts,
                                              const float* __restrict__ centroid,
                                              float* __restrict__ dpart) {
    __shared__ int   pbuf[PERMBUF];
    __shared__ float cen[D_DIM];
    __shared__ float wsum[8];
    int g = blockIdx.x / NSLC, s = blockIdx.x % NSLC;
    int off = offsets[g], len = counts[g];
    int lo = off + (int)(((long)len * s) / NSLC);
    int hi = off + (int)(((long)len * (s + 1)) / NSLC);
    int slen = hi - lo;
    int t = threadIdx.x, lane = t & 63, w = t >> 6;

    for (int j = t; j < slen; j += 512) pbuf[j] = perm[lo + j];
    if (t < D_DIM) cen[t] = centroid[g * D_DIM + t];
    __syncthreads();

    int cd = (lane * 4) & 127;
    float4 c = make_float4(cen[cd], cen[cd + 1], cen[cd + 2], cen[cd + 3]);

    float sacc = 0.f;
    for (int i = w * 4; i < slen; i += 32) {
#pragma unroll
        for (int u = 0; u < 4; ++u) {
            int j  = i + u;
            int jj = (j < slen) ? j : (slen - 1);
            int b  = pbuf[jj];
            float4 x = X4[(size_t)b * 64 + lane];
            float dx = x.x - c.x, dy = x.y - c.y, dz = x.z - c.z, dw = x.w - c.w;
            float d = dx * dx + dy * dy + dz * dz + dw * dw;
#pragma unroll
            for (int m = 1; m <= 16; m <<= 1) d += __shfl_xor(d, m);
            if (j < slen) sacc += sqrtf(sqrtf(d));   // sqrt(||x-c||)
        }
    }
    float tot = sacc + __shfl_xor(sacc, 32);   // fold the two views
    if (lane == 0) wsum[w] = tot;
    __syncthreads();
    if (t == 0) {
        float v = 0.f;
        for (int r = 0; r < 8; ++r) v += wsum[r];
        dpart[g * NSLC + s] = v;
    }
}

// ---------------------------------------------------------------------------
// k_final: single block, 128 threads (thread t = group t).
// ---------------------------------------------------------------------------
__global__ __launch_bounds__(128) void k_final(const float* __restrict__ dpart,
                                               const float* __restrict__ countsf,
                                               const float* __restrict__ centroid,
                                               float* __restrict__ out) {
    __shared__ float srt[G_GR];
    __shared__ float red[G_GR];
    __shared__ float coc[D_DIM];
    int t = threadIdx.x;

    float ds = 0.f;
    for (int s = 0; s < NSLC; ++s) ds += dpart[t * NSLC + s];
    float cnt  = countsf[t];
    float dens = (cnt > 1.f) ? (ds / cnt) / logf(cnt + 10.f) : 0.f;

    red[t] = dens;
    __syncthreads();
    for (int s = 64; s > 0; s >>= 1) {
        if (t < s) red[t] = fmaxf(red[t], red[t + s]);
        __syncthreads();
    }
    float dmax = red[0];
    __syncthreads();
    if (!(cnt > 1.f)) dens = dmax;

    // bitonic sort ascending
    srt[t] = dens;
    __syncthreads();
    for (int k = 2; k <= G_GR; k <<= 1) {
        for (int j = k >> 1; j > 0; j >>= 1) {
            int ixj = t ^ j;
            if (ixj > t) {
                float a = srt[t], b = srt[ixj];
                bool up = ((t & k) == 0);
                if ((a > b) == up) { srt[t] = b; srt[ixj] = a; }
            }
            __syncthreads();
        }
    }
    double p10 = 0.10 * 127.0, p90 = 0.90 * 127.0;
    int   i10 = (int)p10,           i90 = (int)p90;
    float f10 = (float)(p10 - i10), f90 = (float)(p90 - i90);
    float lo = srt[i10] + f10 * (srt[i10 + 1] - srt[i10]);
    float hi = srt[i90] + f90 * (srt[i90 + 1] - srt[i90]);
    dens = fminf(fmaxf(dens, lo), hi);

    red[t] = dens;
    __syncthreads();
    for (int s = 64; s > 0; s >>= 1) {
        if (t < s) red[t] += red[t + s];
        __syncthreads();
    }
    float dmean = red[0] / 128.f;
    __syncthreads();
    dens = 0.1f * dens / dmean;

    float cs = 0.f;
    for (int g = 0; g < G_GR; ++g) cs += centroid[g * D_DIM + t];
    coc[t] = cs / 128.f;
    __syncthreads();

    float dot = 0.f;
    for (int d = 0; d < D_DIM; ++d) dot += centroid[t * D_DIM + d] * coc[d];
    float sim = expf(dot / dens);

    red[t] = sim;
    __syncthreads();
    for (int s = 64; s > 0; s >>= 1) {
        if (t < s) red[t] = fmaxf(red[t], red[t + s]);
        __syncthreads();
    }
    float smax = red[0];
    __syncthreads();
    red[t] = sim - smax;
    __syncthreads();
    for (int s = 64; s > 0; s >>= 1) {
        if (t < s) red[t] += red[t + s];
        __syncthreads();
    }
    if (t == 0) out[0] = -(red[0] / 128.f);
}

// ---------------------------------------------------------------------------
extern "C" void kernel_launch(void* const* d_in, const int* in_sizes, int n_in,
                              void* d_out, int out_size, void* d_ws, size_t ws_size,
                              hipStream_t stream) {
    const float* X       = (const float*)d_in[0];
    const int*   subject = (const int*)d_in[1];
    const int*   labels  = (const int*)d_in[2];
    float*       out     = (float*)d_out;
    char*        ws      = (char*)d_ws;

    int*   counts   = (int*)(ws + 0);
    int*   offsets  = (int*)(ws + 512);
    int*   cursor   = (int*)(ws + 1024);
    float* countsf  = (float*)(ws + 1536);
    int*   perm     = (int*)(ws + 2048);                         // 512 KiB
    float* part     = (float*)(ws + 2048 + 524288);              // 1 MiB
    float* centroid = (float*)(ws + 2048 + 524288 + 1048576);    // 64 KiB
    float* dpart    = (float*)(ws + 2048 + 524288 + 1048576 + 65536); // 8 KiB

    hipMemsetAsync(counts, 0, 512, stream);
    k_hist  <<<256, 256, 0, stream>>>(subject, labels, counts);
    k_prefix<<<1, 128, 0, stream>>>(counts, offsets, cursor, countsf);
    k_slot  <<<256, 256, 0, stream>>>(subject, labels, cursor, perm);
    k_psum  <<<G_GR * NSLC, 512, 0, stream>>>((const float4*)X, perm, offsets, counts, part);
    k_reduce<<<(G_GR * D_DIM + 255) / 256, 256, 0, stream>>>(part, counts, centroid);
    k_dist  <<<G_GR * NSLC, 512, 0, stream>>>((const float4*)X, perm, offsets, counts, centroid, dpart);
    k_final <<<1, 128, 0, stream>>>(dpart, countsf, centroid, out);
}

// Round 3
// 244.649 us; speedup vs baseline: 1.9969x; 1.4356x over previous
//
#include <hip/hip_runtime.h>
#include <cstdint>
#include <cstddef>

#define BPTS  131072
#define D_DIM 128
#define G_GR  128
#define NL    8
#define NSLC  16            // slices per group -> 2048 blocks for heavy passes
#define PERMBUF 256         // LDS perm cache; max slice len ~72 for B=131072
#define NBLK_S  64          // sort blocks
#define PTS_PER (BPTS / NBLK_S)   // 2048 contiguous points per sort block

// ---------------------------------------------------------------------------
// k_hist_blk: per-block histogram of group ids -> hblk[blk][128]
// ---------------------------------------------------------------------------
__global__ __launch_bounds__(256) void k_hist_blk(const int* __restrict__ sub,
                                                  const int* __restrict__ lab,
                                                  int* __restrict__ hblk) {
    __shared__ int h[G_GR];
    int t = threadIdx.x, blk = blockIdx.x;
    if (t < G_GR) h[t] = 0;
    __syncthreads();
    int base = blk * PTS_PER;
    for (int i = t; i < PTS_PER; i += 256)
        atomicAdd(&h[sub[base + i] * NL + lab[base + i]], 1);
    __syncthreads();
    if (t < G_GR) hblk[blk * G_GR + t] = h[t];
}

// ---------------------------------------------------------------------------
// k_prefix: totals, group-exclusive-prefix offsets, per-(block,group) bases.
// Single block, 128 threads (thread t = group t). Deterministic.
// ---------------------------------------------------------------------------
__global__ __launch_bounds__(128) void k_prefix(const int* __restrict__ hblk,
                                                int* __restrict__ counts,
                                                int* __restrict__ offsets,
                                                int* __restrict__ base,
                                                float* __restrict__ countsf) {
    __shared__ int tot[G_GR];
    int t = threadIdx.x;
    int s = 0;
    for (int b = 0; b < NBLK_S; ++b) s += hblk[b * G_GR + t];
    tot[t] = s;
    counts[t] = s;
    countsf[t] = 2.0f * (float)s;
    __syncthreads();
    int o = 0;
    for (int j = 0; j < t; ++j) o += tot[j];
    offsets[t] = o;
    int run = o;
    for (int b = 0; b < NBLK_S; ++b) {
        base[b * G_GR + t] = run;
        run += hblk[b * G_GR + t];
    }
}

// ---------------------------------------------------------------------------
// k_scatter: perm[slot] = point index; slot from per-block LDS cursor seeded
// with the deterministic base. Zero global atomics.
// ---------------------------------------------------------------------------
__global__ __launch_bounds__(256) void k_scatter(const int* __restrict__ sub,
                                                 const int* __restrict__ lab,
                                                 const int* __restrict__ base,
                                                 int* __restrict__ perm) {
    __shared__ int cur[G_GR];
    int t = threadIdx.x, blk = blockIdx.x;
    if (t < G_GR) cur[t] = base[blk * G_GR + t];
    __syncthreads();
    int b0 = blk * PTS_PER;
    for (int i = t; i < PTS_PER; i += 256) {
        int p = b0 + i;
        int g = sub[p] * NL + lab[p];
        int s = atomicAdd(&cur[g], 1);
        perm[s] = p;
    }
}

// ---------------------------------------------------------------------------
// k_psum: block (g,s) sums its slice of group g's points. 4 waves, wave-per-
// point, unroll 8 (8 KiB in flight/wave), register accumulate, zero atomics.
// ---------------------------------------------------------------------------
__global__ __launch_bounds__(256) void k_psum(const float4* __restrict__ X4,
                                              const int* __restrict__ perm,
                                              const int* __restrict__ offsets,
                                              const int* __restrict__ counts,
                                              float* __restrict__ part) {
    __shared__ int   pbuf[PERMBUF];
    __shared__ float red[4 * 256];       // 4 KiB
    int g = blockIdx.x / NSLC, s = blockIdx.x % NSLC;
    int off = offsets[g], len = counts[g];
    int lo = off + (int)(((long)len * s) / NSLC);
    int hi = off + (int)(((long)len * (s + 1)) / NSLC);
    int slen = hi - lo;
    int t = threadIdx.x, lane = t & 63, w = t >> 6;

    for (int j = t; j < slen; j += 256) pbuf[j] = perm[lo + j];
    __syncthreads();

    float4 acc = make_float4(0.f, 0.f, 0.f, 0.f);
    for (int i = w * 8; i < slen; i += 32) {
#pragma unroll
        for (int u = 0; u < 8; ++u) {
            int j  = i + u;
            int jj = (j < slen) ? j : (slen - 1);
            int b  = pbuf[jj];
            float4 x = X4[(size_t)b * 64 + lane];
            if (j < slen) { acc.x += x.x; acc.y += x.y; acc.z += x.z; acc.w += x.w; }
        }
    }
    red[w * 256 + lane * 4 + 0] = acc.x;
    red[w * 256 + lane * 4 + 1] = acc.y;
    red[w * 256 + lane * 4 + 2] = acc.z;
    red[w * 256 + lane * 4 + 3] = acc.w;
    __syncthreads();
    if (t < 128) {                        // fold 4 wave copies + the two views
        float v = 0.f;
        for (int r = 0; r < 4; ++r) v += red[r * 256 + t] + red[r * 256 + t + 128];
        part[(size_t)(g * NSLC + s) * 128 + t] = v;
    }
}

// ---------------------------------------------------------------------------
// k_reduce: centroid[g][d] = sum of slice partials / (2n)
// ---------------------------------------------------------------------------
__global__ __launch_bounds__(256) void k_reduce(const float* __restrict__ part,
                                                const int* __restrict__ counts,
                                                float* __restrict__ centroid) {
    int t = blockIdx.x * 256 + threadIdx.x;
    if (t >= G_GR * D_DIM) return;
    int g = t >> 7, d = t & 127;
    float v = 0.f;
    for (int s = 0; s < NSLC; ++s) v += part[(size_t)(g * NSLC + s) * 128 + d];
    int n = counts[g];
    centroid[t] = (n > 0) ? v / (2.0f * (float)n) : 0.f;
}

// ---------------------------------------------------------------------------
// k_dist: block (g,s): per-point per-view ||x-c|| via 32-lane shfl butterfly;
// accumulate sqrt(||x-c||). 4 waves, unroll 8.
// ---------------------------------------------------------------------------
__global__ __launch_bounds__(256) void k_dist(const float4* __restrict__ X4,
                                              const int* __restrict__ perm,
                                              const int* __restrict__ offsets,
                                              const int* __restrict__ counts,
                                              const float* __restrict__ centroid,
                                              float* __restrict__ dpart) {
    __shared__ int   pbuf[PERMBUF];
    __shared__ float cen[D_DIM];
    __shared__ float wsum[4];
    int g = blockIdx.x / NSLC, s = blockIdx.x % NSLC;
    int off = offsets[g], len = counts[g];
    int lo = off + (int)(((long)len * s) / NSLC);
    int hi = off + (int)(((long)len * (s + 1)) / NSLC);
    int slen = hi - lo;
    int t = threadIdx.x, lane = t & 63, w = t >> 6;

    for (int j = t; j < slen; j += 256) pbuf[j] = perm[lo + j];
    if (t < D_DIM) cen[t] = centroid[g * D_DIM + t];
    __syncthreads();

    int cd = (lane * 4) & 127;
    float4 c = make_float4(cen[cd], cen[cd + 1], cen[cd + 2], cen[cd + 3]);

    float sacc = 0.f;
    for (int i = w * 8; i < slen; i += 32) {
#pragma unroll
        for (int u = 0; u < 8; ++u) {
            int j  = i + u;
            int jj = (j < slen) ? j : (slen - 1);
            int b  = pbuf[jj];
            float4 x = X4[(size_t)b * 64 + lane];
            float dx = x.x - c.x, dy = x.y - c.y, dz = x.z - c.z, dw = x.w - c.w;
            float d = dx * dx + dy * dy + dz * dz + dw * dw;
#pragma unroll
            for (int m = 1; m <= 16; m <<= 1) d += __shfl_xor(d, m);
            if (j < slen) sacc += sqrtf(sqrtf(d));   // sqrt(||x-c||)
        }
    }
    float tot = sacc + __shfl_xor(sacc, 32);   // fold the two views
    if (lane == 0) wsum[w] = tot;
    __syncthreads();
    if (t == 0) {
        float v = 0.f;
        for (int r = 0; r < 4; ++r) v += wsum[r];
        dpart[g * NSLC + s] = v;
    }
}

// ---------------------------------------------------------------------------
// k_final: single block, 128 threads (thread t = group t).
// ---------------------------------------------------------------------------
__global__ __launch_bounds__(128) void k_final(const float* __restrict__ dpart,
                                               const float* __restrict__ countsf,
                                               const float* __restrict__ centroid,
                                               float* __restrict__ out) {
    __shared__ float srt[G_GR];
    __shared__ float red[G_GR];
    __shared__ float coc[D_DIM];
    int t = threadIdx.x;

    float ds = 0.f;
    for (int s = 0; s < NSLC; ++s) ds += dpart[t * NSLC + s];
    float cnt  = countsf[t];
    float dens = (cnt > 1.f) ? (ds / cnt) / logf(cnt + 10.f) : 0.f;

    red[t] = dens;
    __syncthreads();
    for (int s = 64; s > 0; s >>= 1) {
        if (t < s) red[t] = fmaxf(red[t], red[t + s]);
        __syncthreads();
    }
    float dmax = red[0];
    __syncthreads();
    if (!(cnt > 1.f)) dens = dmax;

    // bitonic sort ascending
    srt[t] = dens;
    __syncthreads();
    for (int k = 2; k <= G_GR; k <<= 1) {
        for (int j = k >> 1; j > 0; j >>= 1) {
            int ixj = t ^ j;
            if (ixj > t) {
                float a = srt[t], b = srt[ixj];
                bool up = ((t & k) == 0);
                if ((a > b) == up) { srt[t] = b; srt[ixj] = a; }
            }
            __syncthreads();
        }
    }
    double p10 = 0.10 * 127.0, p90 = 0.90 * 127.0;
    int   i10 = (int)p10,           i90 = (int)p90;
    float f10 = (float)(p10 - i10), f90 = (float)(p90 - i90);
    float lo = srt[i10] + f10 * (srt[i10 + 1] - srt[i10]);
    float hi = srt[i90] + f90 * (srt[i90 + 1] - srt[i90]);
    dens = fminf(fmaxf(dens, lo), hi);

    red[t] = dens;
    __syncthreads();
    for (int s = 64; s > 0; s >>= 1) {
        if (t < s) red[t] += red[t + s];
        __syncthreads();
    }
    float dmean = red[0] / 128.f;
    __syncthreads();
    dens = 0.1f * dens / dmean;

    float cs = 0.f;
    for (int g = 0; g < G_GR; ++g) cs += centroid[g * D_DIM + t];
    coc[t] = cs / 128.f;
    __syncthreads();

    float dot = 0.f;
    for (int d = 0; d < D_DIM; ++d) dot += centroid[t * D_DIM + d] * coc[d];
    float sim = expf(dot / dens);

    red[t] = sim;
    __syncthreads();
    for (int s = 64; s > 0; s >>= 1) {
        if (t < s) red[t] = fmaxf(red[t], red[t + s]);
        __syncthreads();
    }
    float smax = red[0];
    __syncthreads();
    red[t] = sim - smax;
    __syncthreads();
    for (int s = 64; s > 0; s >>= 1) {
        if (t < s) red[t] += red[t + s];
        __syncthreads();
    }
    if (t == 0) out[0] = -(red[0] / 128.f);
}

// ---------------------------------------------------------------------------
extern "C" void kernel_launch(void* const* d_in, const int* in_sizes, int n_in,
                              void* d_out, int out_size, void* d_ws, size_t ws_size,
                              hipStream_t stream) {
    const float* X       = (const float*)d_in[0];
    const int*   subject = (const int*)d_in[1];
    const int*   labels  = (const int*)d_in[2];
    float*       out     = (float*)d_out;
    char*        ws      = (char*)d_ws;

    size_t o = 0;
    int*   counts   = (int*)(ws + o);   o += 512;
    int*   offsets  = (int*)(ws + o);   o += 512;
    float* countsf  = (float*)(ws + o); o += 512;
    int*   hblk     = (int*)(ws + o);   o += (size_t)NBLK_S * G_GR * 4;   // 32 KiB
    int*   base     = (int*)(ws + o);   o += (size_t)NBLK_S * G_GR * 4;   // 32 KiB
    int*   perm     = (int*)(ws + o);   o += (size_t)BPTS * 4;            // 512 KiB
    float* part     = (float*)(ws + o); o += (size_t)G_GR * NSLC * 128 * 4; // 1 MiB
    float* centroid = (float*)(ws + o); o += (size_t)G_GR * D_DIM * 4;    // 64 KiB
    float* dpart    = (float*)(ws + o); o += (size_t)G_GR * NSLC * 4;     // 8 KiB

    k_hist_blk<<<NBLK_S, 256, 0, stream>>>(subject, labels, hblk);
    k_prefix  <<<1, 128, 0, stream>>>(hblk, counts, offsets, base, countsf);
    k_scatter <<<NBLK_S, 256, 0, stream>>>(subject, labels, base, perm);
    k_psum    <<<G_GR * NSLC, 256, 0, stream>>>((const float4*)X, perm, offsets, counts, part);
    k_reduce  <<<(G_GR * D_DIM + 255) / 256, 256, 0, stream>>>(part, counts, centroid);
    k_dist    <<<G_GR * NSLC, 256, 0, stream>>>((const float4*)X, perm, offsets, counts, centroid, dpart);
    k_final   <<<1, 128, 0, stream>>>(dpart, countsf, centroid, out);
}